// Round 1
// baseline (178.185 us; speedup 1.0000x reference)
//
#include <hip/hip_runtime.h>

#define SE_C   256
#define SE_B   16
#define SE_HW  16384   // 128*128

// ---------------- Kernel 1: global average pool per (b,c) plane ----------------
__global__ __launch_bounds__(256) void se_pool(const float* __restrict__ U,
                                               float* __restrict__ z) {
    const int plane = blockIdx.x;                       // 0 .. B*C-1
    const float4* Up = (const float4*)(U + (size_t)plane * SE_HW);
    const int t = threadIdx.x;

    float sum = 0.f;
    #pragma unroll
    for (int k = 0; k < 16; ++k) {                      // 16 * 256 * 4 = 16384
        float4 v = Up[t + k * 256];
        sum += (v.x + v.y) + (v.z + v.w);
    }
    // wave (64-lane) shuffle reduce
    #pragma unroll
    for (int off = 32; off > 0; off >>= 1)
        sum += __shfl_down(sum, off, 64);

    __shared__ float wsum[4];
    const int lane = t & 63, wid = t >> 6;
    if (lane == 0) wsum[wid] = sum;
    __syncthreads();
    if (t == 0) {
        float tot = (wsum[0] + wsum[1]) + (wsum[2] + wsum[3]);
        z[plane] = tot * (1.0f / SE_HW);
    }
}

// ---------------- Kernel 2: squeeze (relu) -> excite (sigmoid) ----------------
// one block per batch element; 256 threads
__global__ __launch_bounds__(256) void se_fc(const float* __restrict__ z,
                                             const float* __restrict__ w_sq,  // [C/2, C]
                                             const float* __restrict__ w_ex,  // [C, C/2]
                                             float* __restrict__ s) {
    const int b = blockIdx.x;
    const int t = threadIdx.x;

    __shared__ float zb[SE_C];
    __shared__ float h[SE_C / 2];

    zb[t] = z[b * SE_C + t];
    __syncthreads();

    if (t < SE_C / 2) {
        const float* wr = w_sq + t * SE_C;
        float acc = 0.f;
        #pragma unroll 8
        for (int c = 0; c < SE_C; ++c) acc = fmaf(wr[c], zb[c], acc);
        h[t] = fmaxf(acc, 0.f);
    }
    __syncthreads();

    {
        const float* wr = w_ex + t * (SE_C / 2);
        float acc = 0.f;
        #pragma unroll 8
        for (int c = 0; c < SE_C / 2; ++c) acc = fmaf(wr[c], h[c], acc);
        s[b * SE_C + t] = 1.0f / (1.0f + expf(-acc));
    }
}

// ---------------- Kernel 3: out = U * s[plane], float4 grid-stride ----------------
__global__ __launch_bounds__(256) void se_scale(const float* __restrict__ U,
                                                const float* __restrict__ s,
                                                float* __restrict__ out,
                                                int n4) {
    const int stride = gridDim.x * blockDim.x;
    for (int i = blockIdx.x * blockDim.x + threadIdx.x; i < n4; i += stride) {
        float4 v = ((const float4*)U)[i];
        const float g = s[i >> 12];                     // 4096 float4 per plane
        v.x *= g; v.y *= g; v.z *= g; v.w *= g;
        ((float4*)out)[i] = v;
    }
}

extern "C" void kernel_launch(void* const* d_in, const int* in_sizes, int n_in,
                              void* d_out, int out_size, void* d_ws, size_t ws_size,
                              hipStream_t stream) {
    const float* U    = (const float*)d_in[0];
    const float* w_sq = (const float*)d_in[1];
    const float* w_ex = (const float*)d_in[2];
    float* out = (float*)d_out;

    float* z = (float*)d_ws;             // [B*C] = 4096 floats
    float* s = z + SE_B * SE_C;          // [B*C] = 4096 floats

    se_pool<<<SE_B * SE_C, 256, 0, stream>>>(U, z);
    se_fc<<<SE_B, 256, 0, stream>>>(z, w_sq, w_ex, s);

    const int n4 = SE_B * SE_C * SE_HW / 4;  // 16,777,216 float4s
    se_scale<<<2048, 256, 0, stream>>>(U, s, out, n4);
}

// Round 3
// 135.830 us; speedup vs baseline: 1.3118x; 1.3118x over previous
//
#include <hip/hip_runtime.h>

#define SE_C   256
#define SE_B   16
#define SE_HW  16384   // 128*128

typedef float fx4 __attribute__((ext_vector_type(4)));   // native vector for nt builtins

// ---------------- Kernel 1: global average pool per (b,c) plane ----------------
__global__ __launch_bounds__(256) void se_pool(const float* __restrict__ U,
                                               float* __restrict__ z) {
    const int plane = blockIdx.x;                       // 0 .. B*C-1
    const fx4* Up = (const fx4*)(U + (size_t)plane * SE_HW);
    const int t = threadIdx.x;

    float sum = 0.f;
    #pragma unroll
    for (int k = 0; k < 16; ++k) {                      // 16 * 256 * 4 = 16384 floats
        fx4 v = Up[t + k * 256];
        sum += (v.x + v.y) + (v.z + v.w);
    }
    // wave (64-lane) shuffle reduce
    #pragma unroll
    for (int off = 32; off > 0; off >>= 1)
        sum += __shfl_down(sum, off, 64);

    __shared__ float wsum[4];
    const int lane = t & 63, wid = t >> 6;
    if (lane == 0) wsum[wid] = sum;
    __syncthreads();
    if (t == 0) {
        float tot = (wsum[0] + wsum[1]) + (wsum[2] + wsum[3]);
        z[plane] = tot * (1.0f / SE_HW);
    }
}

// ---------------- Kernel 2: squeeze (relu) -> excite (sigmoid) ----------------
// one block per batch element; 256 threads
__global__ __launch_bounds__(256) void se_fc(const float* __restrict__ z,
                                             const float* __restrict__ w_sq,  // [C/2, C]
                                             const float* __restrict__ w_ex,  // [C, C/2]
                                             float* __restrict__ s) {
    const int b = blockIdx.x;
    const int t = threadIdx.x;

    __shared__ float zb[SE_C];
    __shared__ float h[SE_C / 2];

    zb[t] = z[b * SE_C + t];
    __syncthreads();

    if (t < SE_C / 2) {
        const float* wr = w_sq + t * SE_C;
        float acc = 0.f;
        #pragma unroll 8
        for (int c = 0; c < SE_C; ++c) acc = fmaf(wr[c], zb[c], acc);
        h[t] = fmaxf(acc, 0.f);
    }
    __syncthreads();

    {
        const float* wr = w_ex + t * (SE_C / 2);
        float acc = 0.f;
        #pragma unroll 8
        for (int c = 0; c < SE_C / 2; ++c) acc = fmaf(wr[c], h[c], acc);
        s[b * SE_C + t] = 1.0f / (1.0f + expf(-acc));
    }
}

// ---------------- Kernel 3: out = U * s[plane] ----------------
// One block per (b,c) plane: gate is wave-uniform; nt-stores keep U in L3.
__global__ __launch_bounds__(256) void se_scale(const float* __restrict__ U,
                                                const float* __restrict__ s,
                                                float* __restrict__ out) {
    const int plane = blockIdx.x;
    const float g = s[plane];                            // uniform scalar per block
    const fx4* Up = (const fx4*)(U + (size_t)plane * SE_HW);
    fx4* Op = (fx4*)(out + (size_t)plane * SE_HW);
    const int t = threadIdx.x;

    #pragma unroll
    for (int k = 0; k < 16; ++k) {
        fx4 v = Up[t + k * 256];
        v *= g;
        __builtin_nontemporal_store(v, Op + t + k * 256);
    }
}

extern "C" void kernel_launch(void* const* d_in, const int* in_sizes, int n_in,
                              void* d_out, int out_size, void* d_ws, size_t ws_size,
                              hipStream_t stream) {
    const float* U    = (const float*)d_in[0];
    const float* w_sq = (const float*)d_in[1];
    const float* w_ex = (const float*)d_in[2];
    float* out = (float*)d_out;

    float* z = (float*)d_ws;             // [B*C] = 4096 floats
    float* s = z + SE_B * SE_C;          // [B*C] = 4096 floats

    se_pool<<<SE_B * SE_C, 256, 0, stream>>>(U, z);
    se_fc<<<SE_B, 256, 0, stream>>>(z, w_sq, w_ex, s);
    se_scale<<<SE_B * SE_C, 256, 0, stream>>>(U, s, out);
}